// Round 3
// baseline (2262.159 us; speedup 1.0000x reference)
//
#include <hip/hip_runtime.h>

// ---------------- problem constants ----------------
#define NN    8192
#define KK    32
#define DD    64
#define DID   32
#define HD    256
#define BS    4
#define TT    8
#define DSCAN 1024
#define TILE  32   // rows (nodes) per block

// ---------------- device-global workspace (mutable state only) ----------------
// Offsets in floats, all multiples of 64 (16B-aligned).
#define OFF_H      0u          // BS*NN*DD = 2097152
#define OFF_MSGS   2097152u    // 2097152
#define OFF_WCONN  4194304u    // BS*NN*KK = 1048576
#define OFF_RECV   5242880u    // 2097152
#define OFF_DECAY  7340032u    // BS*NN = 32768
#define OFF_ID0    7372800u    // NN*DID = 262144
#define OFF_ID1    7634944u    // 262144
#define OFF_ACC    7897088u    // BS*NN*DID = 1048576
#define WS_TOTAL   8945664u    // 35.8 MB

__device__ float g_ws[WS_TOTAL];

// ---------------- numeric helpers ----------------
__device__ __forceinline__ float fast_sigmoid(float x) { return 1.f / (1.f + __expf(-x)); }
__device__ __forceinline__ float fast_silu(float x)    { return x / (1.f + __expf(-x)); }
__device__ __forceinline__ float fast_tanh(float x) {
    float ax = fabsf(x);
    float t  = __expf(-2.f * ax);
    float r  = (1.f - t) / (1.f + t);
    return copysignf(r, x);
}

// ---------------- init: seed mutable state from f32 inputs ----------------
struct Seg { const float* src; unsigned int dst_off; unsigned int len4; }; // len in float4s
struct InitArgs { Seg seg[4]; };

__global__ void init_copy(InitArgs a, unsigned int total4) {
    unsigned int i = blockIdx.x * 256 + threadIdx.x;
    if (i >= total4) return;
#pragma unroll
    for (int s = 0; s < 4; ++s) {
        unsigned int L = a.seg[s].len4;
        if (i < L) {
            const float4 v = ((const float4*)a.seg[s].src)[i];
            *(float4*)&g_ws[a.seg[s].dst_off + 4u * i] = v;
            return;
        }
        i -= L;
    }
}

// ---------------- shared MLP building blocks ----------------
// layer1: Hs[r][j] = silu( sum_i Xs[r][i]*W[i*HD+j] + bias[j] ), IN = contraction dim
// 256 threads: thread = rg*128 + jj ; owns cols {jj, jj+128}, rows rg*16 .. rg*16+15
template<int IN>
__device__ __forceinline__ void layer1_silu(const float (&Xs)[TILE][HD], float (&Hs)[TILE][HD],
                                            const float* __restrict__ W,
                                            const float* __restrict__ bias, int tid) {
    const int rg = tid >> 7;
    const int jj = tid & 127;
    float a0[16], a1[16];
    const float b0 = bias[jj], b1 = bias[jj + 128];
#pragma unroll
    for (int r = 0; r < 16; ++r) { a0[r] = b0; a1[r] = b1; }
#pragma unroll 2
    for (int i = 0; i < IN; i += 4) {
        const float w00 = W[(i + 0) * HD + jj];
        const float w01 = W[(i + 1) * HD + jj];
        const float w02 = W[(i + 2) * HD + jj];
        const float w03 = W[(i + 3) * HD + jj];
        const float w10 = W[(i + 0) * HD + jj + 128];
        const float w11 = W[(i + 1) * HD + jj + 128];
        const float w12 = W[(i + 2) * HD + jj + 128];
        const float w13 = W[(i + 3) * HD + jj + 128];
#pragma unroll
        for (int r = 0; r < 16; ++r) {
            const float4 x = *(const float4*)&Xs[rg * 16 + r][i];
            a0[r] = fmaf(x.x, w00, fmaf(x.y, w01, fmaf(x.z, w02, fmaf(x.w, w03, a0[r]))));
            a1[r] = fmaf(x.x, w10, fmaf(x.y, w11, fmaf(x.z, w12, fmaf(x.w, w13, a1[r]))));
        }
    }
#pragma unroll
    for (int r = 0; r < 16; ++r) {
        Hs[rg * 16 + r][jj]       = fast_silu(a0[r]);
        Hs[rg * 16 + r][jj + 128] = fast_silu(a1[r]);
    }
}

// layer2 accumulators: a[rr] = bias[o] + sum_i Hs[rg*8+rr][i]*W[i*OC+o]
// 256 threads: thread = rg*64 + o ; o in 0..63, rows rg*8 .. rg*8+7
template<int OC>
__device__ __forceinline__ void layer2_acc(const float (&Hs)[TILE][HD],
                                           const float* __restrict__ W,
                                           const float* __restrict__ bias,
                                           int tid, float (&a)[8]) {
    const int o  = tid & 63;
    const int rg = tid >> 6;
    const float bb = bias[o];
#pragma unroll
    for (int r = 0; r < 8; ++r) a[r] = bb;
#pragma unroll 2
    for (int i = 0; i < HD; i += 4) {
        const float w0 = W[(i + 0) * OC + o];
        const float w1 = W[(i + 1) * OC + o];
        const float w2 = W[(i + 2) * OC + o];
        const float w3 = W[(i + 3) * OC + o];
#pragma unroll
        for (int r = 0; r < 8; ++r) {
            const float4 hh = *(const float4*)&Hs[rg * 8 + r][i];
            a[r] = fmaf(hh.x, w0, fmaf(hh.y, w1, fmaf(hh.z, w2, fmaf(hh.w, w3, a[r]))));
        }
    }
}

// ---------------- phase A: gather + mod MLP ----------------
// X cols: 0..31 hebbian | 32..95 h | 96..127 ident | 128..191 received | 192..255 inject
__global__ __launch_bounds__(256, 2) void phaseA_kernel(
    const float* __restrict__ hebb, const int* __restrict__ conn,
    const float* __restrict__ dw1f, const float* __restrict__ db1f,
    const float* __restrict__ dw2f, const float* __restrict__ db2f,
    const float* __restrict__ ccf, int t)
{
    const float* h      = g_ws + OFF_H;
    const float* msgs   = g_ws + OFF_MSGS;
    float*       wconn  = g_ws + OFF_WCONN;
    float*       recv   = g_ws + OFF_RECV;
    float*       decayb = g_ws + OFF_DECAY;
    const float* identR = g_ws + ((t & 1) ? OFF_ID1 : OFF_ID0);
    float*       acc    = g_ws + OFF_ACC;

    __shared__ float Xs[TILE][HD];   // 32 KB
    __shared__ float Hs[TILE][HD];   // 32 KB (first 8 KB aliased as wsig/idx before layer1)
    float* wsigp = &Hs[0][0];        // [TILE][KK] floats (4 KB)
    float* idxfp = &Hs[4][0];        // [TILE][KK] int-bits stored as float (4 KB)

    const int tid = threadIdx.x;
    const int b   = blockIdx.x >> 8;
    const int n0  = (blockIdx.x & 255) * TILE;

    for (int i = tid; i < TILE * KK; i += 256) {
        const int r = i >> 5, k = i & 31;
        const size_t row = (size_t)(b * NN + n0 + r);
        wsigp[r * KK + k] = fast_sigmoid(wconn[row * KK + k]);
        idxfp[r * KK + k] = __int_as_float(conn[(size_t)(n0 + r) * KK + k]);
        Xs[r][k] = hebb[row * KK + k];
    }
    for (int i = tid; i < TILE * DD; i += 256) {
        const int r = i >> 6, d = i & 63;
        Xs[r][32 + d]  = h[(size_t)(b * NN + n0 + r) * DD + d];
        Xs[r][192 + d] = ccf[(size_t)(b * TT + t) * DSCAN + (n0 >> 9) * DD + d];
    }
    for (int i = tid; i < TILE * DID; i += 256) {
        const int r = i >> 5, j = i & 31;
        Xs[r][96 + j] = identR[(size_t)(n0 + r) * DID + j];
    }
    __syncthreads();

    // gather: received[r][d] = sum_k wsig[r][k] * msgs[b][idx[r][k]][d]
    {
        const int d = tid & 63, r0 = tid >> 6;
        const float* mb = msgs + (size_t)b * NN * DD + d;
        for (int r = r0; r < TILE; r += 4) {
            float a = 0.f;
#pragma unroll
            for (int k = 0; k < KK; ++k) {
                const int idx = __float_as_int(idxfp[r * KK + k]);
                a = fmaf(wsigp[r * KK + k], mb[(size_t)idx * DD], a);
            }
            Xs[r][128 + d] = a;
            recv[(size_t)(b * NN + n0 + r) * DD + d] = a;
        }
    }
    __syncthreads();   // gather done; wsig/idx (in Hs) now dead -> layer1 may overwrite Hs

    layer1_silu<HD>(Xs, Hs, dw1f, db1f, tid);
    __syncthreads();

    {
        float a[8];
        layer2_acc<65>(Hs, dw2f, db2f, tid, a);
        const int o = tid & 63, rg = tid >> 6;
#pragma unroll
        for (int rr = 0; rr < 8; ++rr) {
            const int r = rg * 8 + rr, n = n0 + r;
            const float v = a[rr];
            if (o < 32)        wconn[((size_t)b * NN + n) * KK + o] = v;       // w_new
            else if (o == 32)  decayb[b * NN + n] = fast_sigmoid(v);           // decay
            else               acc[((size_t)b * NN + n) * DID + (o - 33)] = v; // ident delta 0..30
        }
        // column 64 -> ident delta j=31
        if (tid < TILE) {
            const int r = tid;
            float aa = db2f[64];
            for (int i = 0; i < HD; i += 4) {
                const float4 hh = *(const float4*)&Hs[r][i];
                aa = fmaf(hh.x, dw2f[(i + 0) * 65 + 64],
                     fmaf(hh.y, dw2f[(i + 1) * 65 + 64],
                     fmaf(hh.z, dw2f[(i + 2) * 65 + 64],
                     fmaf(hh.w, dw2f[(i + 3) * 65 + 64], aa))));
            }
            acc[((size_t)b * NN + n0 + r) * DID + 31] = aa;
        }
    }
}

// ---------------- phase B: ident merge + state MLP + msg MLP ----------------
// state X cols: 0..63 recv | 64..127 inject | 128..191 h_old | 192..223 ident_new
// msg   X cols: 0..63 h_new | 64..95 ident_new
__global__ __launch_bounds__(256, 2) void phaseB_kernel(
    const float* __restrict__ sw1f, const float* __restrict__ sb1f,
    const float* __restrict__ sw2f, const float* __restrict__ sb2f,
    const float* __restrict__ mw1f, const float* __restrict__ mb1f,
    const float* __restrict__ mw2f, const float* __restrict__ mb2f,
    const float* __restrict__ ccf, float* __restrict__ out, int t)
{
    float*       h      = g_ws + OFF_H;
    float*       msgs   = g_ws + OFF_MSGS;
    const float* recv   = g_ws + OFF_RECV;
    const float* decayb = g_ws + OFF_DECAY;
    const float* identR = g_ws + ((t & 1) ? OFF_ID1 : OFF_ID0);
    float*       identW = g_ws + ((t & 1) ? OFF_ID0 : OFF_ID1);
    const float* acc    = g_ws + OFF_ACC;

    __shared__ float Xs[TILE][HD];   // 32 KB
    __shared__ float Hs[TILE][HD];   // 32 KB

    const int tid = threadIdx.x;
    const int b   = blockIdx.x >> 8;
    const int n0  = (blockIdx.x & 255) * TILE;

    // ident_new = ident + mean_b(acc); every block computes it, b==0 blocks publish it
    for (int i = tid; i < TILE * DID; i += 256) {
        const int r = i >> 5, j = i & 31;
        const int n = n0 + r;
        float s = acc[((size_t)0 * NN + n) * DID + j];
        s += acc[((size_t)1 * NN + n) * DID + j];
        s += acc[((size_t)2 * NN + n) * DID + j];
        s += acc[((size_t)3 * NN + n) * DID + j];
        const float v = identR[(size_t)n * DID + j] + 0.25f * s;
        Xs[r][192 + j] = v;
        if (b == 0) identW[(size_t)n * DID + j] = v;
    }
    for (int i = tid; i < TILE * DD; i += 256) {
        const int r = i >> 6, d = i & 63;
        const size_t row = (size_t)(b * NN + n0 + r);
        Xs[r][d]       = recv[row * DD + d];
        Xs[r][64 + d]  = ccf[(size_t)(b * TT + t) * DSCAN + (n0 >> 9) * DD + d];
        Xs[r][128 + d] = h[row * DD + d];
    }
    __syncthreads();

    layer1_silu<224>(Xs, Hs, sw1f, sb1f, tid);
    __syncthreads();

    {
        float a[8];
        layer2_acc<64>(Hs, sw2f, sb2f, tid, a);
        const int o = tid & 63, rg = tid >> 6;
#pragma unroll
        for (int rr = 0; rr < 8; ++rr) {
            const int r = rg * 8 + rr, n = n0 + r;
            const float hw = fast_tanh(a[rr]);
            const float dc = decayb[b * NN + n];
            const float hn = fmaf(dc, Xs[r][128 + o], (1.f - dc) * hw);
            h[((size_t)b * NN + n) * DD + o] = hn;
            out[(((size_t)b * TT + t) * NN + n) * DD + o] = hn;
            Xs[r][o] = hn;                                  // msg-MLP input col 0..63
        }
        // ident_new -> msg input cols 64..95 (from cols 192..223, disjoint ranges)
        for (int i = tid; i < TILE * DID; i += 256) {
            const int r = i >> 5, j = i & 31;
            Xs[r][64 + j] = Xs[r][192 + j];
        }
    }
    __syncthreads();

    layer1_silu<96>(Xs, Hs, mw1f, mb1f, tid);
    __syncthreads();

    {
        float a[8];
        layer2_acc<64>(Hs, mw2f, mb2f, tid, a);
        const int o = tid & 63, rg = tid >> 6;
#pragma unroll
        for (int rr = 0; rr < 8; ++rr) {
            const int r = rg * 8 + rr, n = n0 + r;
            msgs[((size_t)b * NN + n) * DD + o] = fast_tanh(a[rr]);
        }
    }
}

// ---------------- launch ----------------
extern "C" void kernel_launch(void* const* d_in, const int* in_sizes, int n_in,
                              void* d_out, int out_size, void* d_ws, size_t ws_size,
                              hipStream_t stream)
{
    (void)in_sizes; (void)n_in; (void)out_size; (void)d_ws; (void)ws_size;

    const float* cc   = (const float*)d_in[0];
    const float* h0   = (const float*)d_in[1];
    const float* m0   = (const float*)d_in[2];
    const float* w0   = (const float*)d_in[3];
    const float* hebb = (const float*)d_in[4];
    const float* idn  = (const float*)d_in[5];
    const float* sw1  = (const float*)d_in[6];
    const float* sb1  = (const float*)d_in[7];
    const float* sw2  = (const float*)d_in[8];
    const float* sb2  = (const float*)d_in[9];
    const float* mw1  = (const float*)d_in[10];
    const float* mb1  = (const float*)d_in[11];
    const float* mw2  = (const float*)d_in[12];
    const float* mb2  = (const float*)d_in[13];
    const float* dw1  = (const float*)d_in[14];
    const float* db1  = (const float*)d_in[15];
    const float* dw2  = (const float*)d_in[16];
    const float* db2  = (const float*)d_in[17];
    const int*   conn = (const int*)d_in[18];

    InitArgs ia;
    ia.seg[0] = { h0,  OFF_H,     (BS * NN * DD) / 4 };
    ia.seg[1] = { m0,  OFF_MSGS,  (BS * NN * DD) / 4 };
    ia.seg[2] = { w0,  OFF_WCONN, (BS * NN * KK) / 4 };
    ia.seg[3] = { idn, OFF_ID0,   (NN * DID) / 4 };
    const unsigned int TOT4 = (BS * NN * DD) / 4 * 2 + (BS * NN * KK) / 4 + (NN * DID) / 4;
    init_copy<<<(TOT4 + 255) / 256, 256, 0, stream>>>(ia, TOT4);

    float* outp = (float*)d_out;
    const int grid = BS * (NN / TILE);   // 1024 blocks

    for (int t = 0; t < TT; ++t) {
        phaseA_kernel<<<grid, 256, 0, stream>>>(hebb, conn, dw1, db1, dw2, db2, cc, t);
        phaseB_kernel<<<grid, 256, 0, stream>>>(sw1, sb1, sw2, sb2,
                                                mw1, mb1, mw2, mb2,
                                                cc, outp, t);
    }
}

// Round 4
// 635.466 us; speedup vs baseline: 3.5598x; 3.5598x over previous
//
#include <hip/hip_runtime.h>

// ---------------- problem constants ----------------
#define NN    8192
#define KK    32
#define DD    64
#define DID   32
#define HD    256
#define BS    4
#define TT    8
#define DSCAN 1024
#define TILE  32     // rows (nodes) per block
#define XSTR  264    // LDS row stride in f16 (264*2=528B: 16B-aligned rows, 2-way bank aliasing = free)

typedef _Float16 f16;
typedef f16   f16x8 __attribute__((ext_vector_type(8)));
typedef float f32x4 __attribute__((ext_vector_type(4)));

// ---------------- device-global workspace (mutable f32 state) ----------------
#define OFF_H      0u          // BS*NN*DD = 2097152
#define OFF_MSGS   2097152u
#define OFF_WCONN  4194304u    // BS*NN*KK = 1048576
#define OFF_RECV   5242880u    // 2097152
#define OFF_DECAY  7340032u    // BS*NN = 32768
#define OFF_ID0    7372800u    // NN*DID = 262144
#define OFF_ID1    7634944u
#define OFF_ACC    7897088u    // BS*NN*DID = 1048576
#define WS_TOTAL   8945664u

__device__ float g_ws[WS_TOTAL];

// ---------------- pre-swizzled f16 weights (MFMA B-fragment order) ----------------
// frag[((ct*KB + kb)*64 + lane)*8 + j] = W[kb*32 + (lane>>4)*8 + j][ct*16 + (lane&15)]
#define OFF16_DW1  0u        // 16ct*8kb*512 = 65536
#define OFF16_DW2  65536u    // 5ct (pad 65->80 cols)*8kb*512 = 20480
#define OFF16_SW1  86016u    // 16*7*512 = 57344
#define OFF16_SW2  143360u   // 4*8*512 = 16384
#define OFF16_MW1  159744u   // 16*3*512 = 24576
#define OFF16_MW2  184320u   // 16384
#define W16_TOTAL  200704u

__device__ f16 g_wf16[W16_TOTAL];

// ---------------- numeric helpers ----------------
__device__ __forceinline__ float fast_sigmoid(float x) { return 1.f / (1.f + __expf(-x)); }
__device__ __forceinline__ float fast_silu(float x)    { return x / (1.f + __expf(-x)); }
__device__ __forceinline__ float fast_tanh(float x) {
    float ax = fabsf(x);
    float t  = __expf(-2.f * ax);
    float r  = (1.f - t) / (1.f + t);
    return copysignf(r, x);
}

// ---------------- init kernels ----------------
struct Seg { const float* src; unsigned int dst_off; unsigned int len4; };
struct InitArgs { Seg seg[4]; };

__global__ void init_copy(InitArgs a, unsigned int total4) {
    unsigned int i = blockIdx.x * 256 + threadIdx.x;
    if (i >= total4) return;
#pragma unroll
    for (int s = 0; s < 4; ++s) {
        unsigned int L = a.seg[s].len4;
        if (i < L) {
            const float4 v = ((const float4*)a.seg[s].src)[i];
            *(float4*)&g_ws[a.seg[s].dst_off + 4u * i] = v;
            return;
        }
        i -= L;
    }
}

struct WL { const float* W; int Nsrc; int KB; unsigned int dst; int sz; };
struct WArgs { WL l[6]; };

__global__ void init_wswz(WArgs a, int total) {
    int i = blockIdx.x * 256 + threadIdx.x;
    if (i >= total) return;
#pragma unroll
    for (int s = 0; s < 6; ++s) {
        const int sz = a.l[s].sz;
        if (i < sz) {
            const int KB  = a.l[s].KB;
            const int ct  = i / (KB * 512);
            const int r   = i - ct * KB * 512;
            const int kb  = r >> 9;
            const int r2  = r & 511;
            const int ln  = r2 >> 3;
            const int j   = r2 & 7;
            const int k   = kb * 32 + (ln >> 4) * 8 + j;
            const int n   = ct * 16 + (ln & 15);
            const float v = (n < a.l[s].Nsrc) ? a.l[s].W[k * a.l[s].Nsrc + n] : 0.f;
            g_wf16[a.l[s].dst + i] = (f16)v;
            return;
        }
        i -= sz;
    }
}

// ---------------- MFMA layer1 (N=256, silu) : Xs -> Hs ----------------
template<int KB>
__device__ __forceinline__ void mfma_layer1(const f16 (&Xs)[TILE][XSTR], f16 (&Hs)[TILE][XSTR],
                                            const f16* __restrict__ wp,
                                            const float* __restrict__ bias, int tid) {
    const int wv = tid >> 6, lane = tid & 63, lrow = lane & 15, quad = lane >> 4;
    f32x4 acc[2][4];
#pragma unroll
    for (int m = 0; m < 2; ++m)
#pragma unroll
        for (int c = 0; c < 4; ++c) acc[m][c] = (f32x4){0.f, 0.f, 0.f, 0.f};
#pragma unroll
    for (int kb = 0; kb < KB; ++kb) {
        const f16x8 a0 = *(const f16x8*)&Xs[lrow][kb * 32 + quad * 8];
        const f16x8 a1 = *(const f16x8*)&Xs[16 + lrow][kb * 32 + quad * 8];
#pragma unroll
        for (int c = 0; c < 4; ++c) {
            const f16x8 bf = *(const f16x8*)&wp[(((4 * wv + c) * KB + kb) * 64 + lane) * 8];
            acc[0][c] = __builtin_amdgcn_mfma_f32_16x16x32_f16(a0, bf, acc[0][c], 0, 0, 0);
            acc[1][c] = __builtin_amdgcn_mfma_f32_16x16x32_f16(a1, bf, acc[1][c], 0, 0, 0);
        }
    }
#pragma unroll
    for (int mt = 0; mt < 2; ++mt)
#pragma unroll
        for (int c = 0; c < 4; ++c) {
            const int col = (4 * wv + c) * 16 + lrow;
            const float bb = bias[col];
#pragma unroll
            for (int reg = 0; reg < 4; ++reg)
                Hs[mt * 16 + quad * 4 + reg][col] = (f16)fast_silu(acc[mt][c][reg] + bb);
        }
}

// ---------------- phase A: gather + mod MLP ----------------
__global__ __launch_bounds__(256, 4) void phaseA_kernel(
    const float* __restrict__ hebb, const int* __restrict__ conn,
    const float* __restrict__ db1f, const float* __restrict__ db2f,
    const float* __restrict__ ccf, int t)
{
    const float* h      = g_ws + OFF_H;
    const float* msgs   = g_ws + OFF_MSGS;
    float*       wconn  = g_ws + OFF_WCONN;
    float*       recv   = g_ws + OFF_RECV;
    float*       decayb = g_ws + OFF_DECAY;
    const float* identR = g_ws + ((t & 1) ? OFF_ID1 : OFF_ID0);
    float*       accb   = g_ws + OFF_ACC;

    __shared__ f16 Xs[TILE][XSTR];   // 16.9 KB
    __shared__ f16 Hs[TILE][XSTR];   // 16.9 KB (first 8 KB aliased as wsig/idx pre-layer1)
    float* wsigp = (float*)&Hs[0][0];                   // 4 KB
    float* idxfp = (float*)((char*)&Hs[0][0] + 4096);   // 4 KB

    const int tid = threadIdx.x;
    const int b   = blockIdx.x >> 8;
    const int n0  = (blockIdx.x & 255) * TILE;

    for (int i = tid; i < TILE * KK; i += 256) {
        const int r = i >> 5, k = i & 31;
        const int row = b * NN + n0 + r;
        wsigp[i] = fast_sigmoid(wconn[(size_t)row * KK + k]);
        idxfp[i] = __int_as_float(conn[(size_t)(n0 + r) * KK + k]);
        Xs[r][k] = (f16)hebb[(size_t)row * KK + k];
    }
    for (int i = tid; i < TILE * DD; i += 256) {
        const int r = i >> 6, d = i & 63;
        Xs[r][32 + d]  = (f16)h[(size_t)(b * NN + n0 + r) * DD + d];
        Xs[r][192 + d] = (f16)ccf[(size_t)(b * TT + t) * DSCAN + (n0 >> 9) * DD + d];
    }
    for (int i = tid; i < TILE * DID; i += 256) {
        const int r = i >> 5, j = i & 31;
        Xs[r][96 + j] = (f16)identR[(size_t)(n0 + r) * DID + j];
    }
    __syncthreads();

    // gather (VALU): received[r][d] = sum_k wsig[r][k] * msgs[b][idx[r][k]][d]
    {
        const int d = tid & 63, r0 = tid >> 6;
        const float* mb = msgs + (size_t)b * NN * DD + d;
        for (int r = r0; r < TILE; r += 4) {
            float a = 0.f;
#pragma unroll
            for (int k = 0; k < KK; ++k) {
                const int idx = __float_as_int(idxfp[r * KK + k]);
                a = fmaf(wsigp[r * KK + k], mb[(size_t)idx * DD], a);
            }
            Xs[r][128 + d] = (f16)a;
            recv[(size_t)(b * NN + n0 + r) * DD + d] = a;
        }
    }
    __syncthreads();   // wsig/idx dead; layer1 may write Hs

    mfma_layer1<8>(Xs, Hs, g_wf16 + OFF16_DW1, db1f, tid);
    __syncthreads();

    // layer2: N=80 (65 used), tiles (ct 0..4, mt 0..1); wave w: (w,0),(w,1); waves 0,1 also (4,w)
    {
        const int wv = tid >> 6, lane = tid & 63, lrow = lane & 15, quad = lane >> 4;
        const f16* wp2 = g_wf16 + OFF16_DW2;
        f32x4 t0 = {0.f,0.f,0.f,0.f}, t1 = t0, t2 = t0;
#pragma unroll
        for (int kb = 0; kb < 8; ++kb) {
            const f16x8 a0 = *(const f16x8*)&Hs[lrow][kb * 32 + quad * 8];
            const f16x8 a1 = *(const f16x8*)&Hs[16 + lrow][kb * 32 + quad * 8];
            const f16x8 b0 = *(const f16x8*)&wp2[((wv * 8 + kb) * 64 + lane) * 8];
            t0 = __builtin_amdgcn_mfma_f32_16x16x32_f16(a0, b0, t0, 0, 0, 0);
            t1 = __builtin_amdgcn_mfma_f32_16x16x32_f16(a1, b0, t1, 0, 0, 0);
            if (wv < 2) {
                const f16x8 b4 = *(const f16x8*)&wp2[((4 * 8 + kb) * 64 + lane) * 8];
                const f16x8 am = (wv == 0) ? a0 : a1;
                t2 = __builtin_amdgcn_mfma_f32_16x16x32_f16(am, b4, t2, 0, 0, 0);
            }
        }
        // scatter epilogue: col o decides destination
        const int ob = wv * 16 + lrow;
        const float bb = (ob < 65) ? db2f[ob] : 0.f;
#pragma unroll
        for (int mt = 0; mt < 2; ++mt) {
            const f32x4 tv = mt ? t1 : t0;
#pragma unroll
            for (int reg = 0; reg < 4; ++reg) {
                const int n = n0 + mt * 16 + quad * 4 + reg;
                const float v = tv[reg] + bb;
                if (ob < 32)       wconn[((size_t)b * NN + n) * KK + ob] = v;
                else if (ob == 32) decayb[b * NN + n] = fast_sigmoid(v);
                else               accb[((size_t)b * NN + n) * DID + (ob - 33)] = v;
            }
        }
        if (wv < 2) {   // ct=4 tile: only col 64 (ident delta j=31) is real
            const int o4 = 64 + lrow;
            if (o4 == 64) {
                const float bb4 = db2f[64];
#pragma unroll
                for (int reg = 0; reg < 4; ++reg) {
                    const int n = n0 + wv * 16 + quad * 4 + reg;
                    accb[((size_t)b * NN + n) * DID + 31] = t2[reg] + bb4;
                }
            }
        }
    }
}

// ---------------- phase B: ident merge + state MLP + msg MLP ----------------
__global__ __launch_bounds__(256, 4) void phaseB_kernel(
    const float* __restrict__ sb1f, const float* __restrict__ sb2f,
    const float* __restrict__ mb1f, const float* __restrict__ mb2f,
    const float* __restrict__ ccf, float* __restrict__ out, int t)
{
    float*       h      = g_ws + OFF_H;
    float*       msgs   = g_ws + OFF_MSGS;
    const float* recv   = g_ws + OFF_RECV;
    const float* decayb = g_ws + OFF_DECAY;
    const float* identR = g_ws + ((t & 1) ? OFF_ID1 : OFF_ID0);
    float*       identW = g_ws + ((t & 1) ? OFF_ID0 : OFF_ID1);
    const float* accb   = g_ws + OFF_ACC;

    __shared__ f16 Xs[TILE][XSTR];
    __shared__ f16 Hs[TILE][XSTR];

    const int tid = threadIdx.x;
    const int b   = blockIdx.x >> 8;
    const int n0  = (blockIdx.x & 255) * TILE;

    // staging: state X = [recv | inject | h_old | ident_new]
    for (int i = tid; i < TILE * DID; i += 256) {
        const int r = i >> 5, j = i & 31;
        const int n = n0 + r;
        float s = accb[((size_t)0 * NN + n) * DID + j];
        s += accb[((size_t)1 * NN + n) * DID + j];
        s += accb[((size_t)2 * NN + n) * DID + j];
        s += accb[((size_t)3 * NN + n) * DID + j];
        const float v = identR[(size_t)n * DID + j] + 0.25f * s;
        Xs[r][192 + j] = (f16)v;
        if (b == 0) identW[(size_t)n * DID + j] = v;
    }
    for (int i = tid; i < TILE * DD; i += 256) {
        const int r = i >> 6, d = i & 63;
        const size_t row = (size_t)(b * NN + n0 + r);
        Xs[r][d]       = (f16)recv[row * DD + d];
        Xs[r][64 + d]  = (f16)ccf[(size_t)(b * TT + t) * DSCAN + (n0 >> 9) * DD + d];
        Xs[r][128 + d] = (f16)h[row * DD + d];
    }
    __syncthreads();

    mfma_layer1<7>(Xs, Hs, g_wf16 + OFF16_SW1, sb1f, tid);
    __syncthreads();

    // state layer2 (N=64): wave w -> (ct=w, mt=0,1); blend + write h/out + stage msg input
    {
        const int wv = tid >> 6, lane = tid & 63, lrow = lane & 15, quad = lane >> 4;
        const f16* wp2 = g_wf16 + OFF16_SW2;
        f32x4 t0 = {0.f,0.f,0.f,0.f}, t1 = t0;
#pragma unroll
        for (int kb = 0; kb < 8; ++kb) {
            const f16x8 a0 = *(const f16x8*)&Hs[lrow][kb * 32 + quad * 8];
            const f16x8 a1 = *(const f16x8*)&Hs[16 + lrow][kb * 32 + quad * 8];
            const f16x8 b0 = *(const f16x8*)&wp2[((wv * 8 + kb) * 64 + lane) * 8];
            t0 = __builtin_amdgcn_mfma_f32_16x16x32_f16(a0, b0, t0, 0, 0, 0);
            t1 = __builtin_amdgcn_mfma_f32_16x16x32_f16(a1, b0, t1, 0, 0, 0);
        }
        const int o = wv * 16 + lrow;
        const float bb = sb2f[o];
#pragma unroll
        for (int mt = 0; mt < 2; ++mt) {
            const f32x4 tv = mt ? t1 : t0;
#pragma unroll
            for (int reg = 0; reg < 4; ++reg) {
                const int r = mt * 16 + quad * 4 + reg;
                const int n = n0 + r;
                const float hw = fast_tanh(tv[reg] + bb);
                const float dc = decayb[b * NN + n];
                const float ho = h[((size_t)b * NN + n) * DD + o];
                const float hn = fmaf(dc, ho, (1.f - dc) * hw);
                h[((size_t)b * NN + n) * DD + o] = hn;
                out[(((size_t)b * TT + t) * NN + n) * DD + o] = hn;
                Xs[r][o] = (f16)hn;          // msg input cols 0..63
            }
        }
        // ident_new -> msg input cols 64..95 (inject cols now dead)
        for (int i = tid; i < TILE * DID; i += 256) {
            const int r = i >> 5, j = i & 31;
            Xs[r][64 + j] = Xs[r][192 + j];
        }
    }
    __syncthreads();

    mfma_layer1<3>(Xs, Hs, g_wf16 + OFF16_MW1, mb1f, tid);
    __syncthreads();

    // msg layer2 (N=64)
    {
        const int wv = tid >> 6, lane = tid & 63, lrow = lane & 15, quad = lane >> 4;
        const f16* wp2 = g_wf16 + OFF16_MW2;
        f32x4 t0 = {0.f,0.f,0.f,0.f}, t1 = t0;
#pragma unroll
        for (int kb = 0; kb < 8; ++kb) {
            const f16x8 a0 = *(const f16x8*)&Hs[lrow][kb * 32 + quad * 8];
            const f16x8 a1 = *(const f16x8*)&Hs[16 + lrow][kb * 32 + quad * 8];
            const f16x8 b0 = *(const f16x8*)&wp2[((wv * 8 + kb) * 64 + lane) * 8];
            t0 = __builtin_amdgcn_mfma_f32_16x16x32_f16(a0, b0, t0, 0, 0, 0);
            t1 = __builtin_amdgcn_mfma_f32_16x16x32_f16(a1, b0, t1, 0, 0, 0);
        }
        const int o = wv * 16 + lrow;
        const float bb = mb2f[o];
#pragma unroll
        for (int mt = 0; mt < 2; ++mt) {
            const f32x4 tv = mt ? t1 : t0;
#pragma unroll
            for (int reg = 0; reg < 4; ++reg) {
                const int n = n0 + mt * 16 + quad * 4 + reg;
                msgs[((size_t)b * NN + n) * DD + o] = fast_tanh(tv[reg] + bb);
            }
        }
    }
}

// ---------------- launch ----------------
extern "C" void kernel_launch(void* const* d_in, const int* in_sizes, int n_in,
                              void* d_out, int out_size, void* d_ws, size_t ws_size,
                              hipStream_t stream)
{
    (void)in_sizes; (void)n_in; (void)out_size; (void)d_ws; (void)ws_size;

    const float* cc   = (const float*)d_in[0];
    const float* h0   = (const float*)d_in[1];
    const float* m0   = (const float*)d_in[2];
    const float* w0   = (const float*)d_in[3];
    const float* hebb = (const float*)d_in[4];
    const float* idn  = (const float*)d_in[5];
    const float* sw1  = (const float*)d_in[6];
    const float* sb1  = (const float*)d_in[7];
    const float* sw2  = (const float*)d_in[8];
    const float* sb2  = (const float*)d_in[9];
    const float* mw1  = (const float*)d_in[10];
    const float* mb1  = (const float*)d_in[11];
    const float* mw2  = (const float*)d_in[12];
    const float* mb2  = (const float*)d_in[13];
    const float* dw1  = (const float*)d_in[14];
    const float* db1  = (const float*)d_in[15];
    const float* dw2  = (const float*)d_in[16];
    const float* db2  = (const float*)d_in[17];
    const int*   conn = (const int*)d_in[18];

    InitArgs ia;
    ia.seg[0] = { h0,  OFF_H,     (BS * NN * DD) / 4 };
    ia.seg[1] = { m0,  OFF_MSGS,  (BS * NN * DD) / 4 };
    ia.seg[2] = { w0,  OFF_WCONN, (BS * NN * KK) / 4 };
    ia.seg[3] = { idn, OFF_ID0,   (NN * DID) / 4 };
    const unsigned int TOT4 = (BS * NN * DD) / 4 * 2 + (BS * NN * KK) / 4 + (NN * DID) / 4;
    init_copy<<<(TOT4 + 255) / 256, 256, 0, stream>>>(ia, TOT4);

    WArgs wa;
    wa.l[0] = { dw1, 256, 8, OFF16_DW1, 16 * 8 * 512 };
    wa.l[1] = { dw2,  65, 8, OFF16_DW2,  5 * 8 * 512 };
    wa.l[2] = { sw1, 256, 7, OFF16_SW1, 16 * 7 * 512 };
    wa.l[3] = { sw2,  64, 8, OFF16_SW2,  4 * 8 * 512 };
    wa.l[4] = { mw1, 256, 3, OFF16_MW1, 16 * 3 * 512 };
    wa.l[5] = { mw2,  64, 8, OFF16_MW2,  4 * 8 * 512 };
    init_wswz<<<(W16_TOTAL + 255) / 256, 256, 0, stream>>>(wa, (int)W16_TOTAL);

    float* outp = (float*)d_out;
    const int grid = BS * (NN / TILE);   // 1024 blocks

    for (int t = 0; t < TT; ++t) {
        phaseA_kernel<<<grid, 256, 0, stream>>>(hebb, conn, db1, db2, cc, t);
        phaseB_kernel<<<grid, 256, 0, stream>>>(sb1, sb2, mb1, mb2, cc, outp, t);
    }
}

// Round 5
// 554.244 us; speedup vs baseline: 4.0815x; 1.1465x over previous
//
#include <hip/hip_runtime.h>

// ---------------- problem constants ----------------
#define NN    8192
#define KK    32
#define DD    64
#define DID   32
#define HD    256
#define BS    4
#define TT    8
#define DSCAN 1024
#define TILE  32     // rows (nodes) per block
#define XSTR  264    // LDS row stride in f16 (264*2=528B: 16B-aligned rows, 2-way bank aliasing = free)

typedef _Float16 f16;
typedef f16   f16x4 __attribute__((ext_vector_type(4)));
typedef f16   f16x8 __attribute__((ext_vector_type(8)));
typedef float f32x4 __attribute__((ext_vector_type(4)));

// ---------------- device-global workspace (mutable state) ----------------
#define OFF_H      0u          // BS*NN*DD f32 = 2097152
#define OFF_MSGS   2097152u
#define OFF_WCONN  4194304u    // BS*NN*KK = 1048576
#define OFF_RECV   5242880u    // BS*NN*DD f16 (half the f32 slots used)
#define OFF_DECAY  7340032u    // BS*NN = 32768
#define OFF_ID0    7372800u    // NN*DID = 262144
#define OFF_ID1    7634944u
#define OFF_ACC    7897088u    // BS*NN*DID = 1048576
#define WS_TOTAL   8945664u

__device__ float g_ws[WS_TOTAL];

// ---------------- pre-swizzled f16 weights (MFMA B-fragment order) ----------------
// frag[((ct*KB + kb)*64 + lane)*8 + j] = W[kb*32 + (lane>>4)*8 + j][ct*16 + (lane&15)]
#define OFF16_DW1  0u        // 16*8*512 = 65536
#define OFF16_DW2  65536u    // 5*8*512 = 20480 (65 cols padded to 80)
#define OFF16_SW1  86016u    // 16*7*512 = 57344
#define OFF16_SW2  143360u   // 4*8*512 = 16384
#define OFF16_MW1  159744u   // 16*3*512 = 24576
#define OFF16_MW2  184320u   // 16384
#define W16_TOTAL  200704u

__device__ f16 g_wf16[W16_TOTAL];

// ---------------- numeric helpers ----------------
__device__ __forceinline__ float fast_sigmoid(float x) { return 1.f / (1.f + __expf(-x)); }
__device__ __forceinline__ float fast_silu(float x)    { return x / (1.f + __expf(-x)); }
__device__ __forceinline__ float fast_tanh(float x) {
    float ax = fabsf(x);
    float t  = __expf(-2.f * ax);
    float r  = (1.f - t) / (1.f + t);
    return copysignf(r, x);
}
__device__ __forceinline__ f16x4 cvt4(float4 v) {
    f16x4 o; o[0] = (f16)v.x; o[1] = (f16)v.y; o[2] = (f16)v.z; o[3] = (f16)v.w; return o;
}

// XCD-aware decode: XCD = blockIdx%8 (round-robin); batch b -> XCDs {2b,2b+1}.
// Each XCD's gather working set = its own batch's msgs (2 MB) -> fits 4 MB L2.
__device__ __forceinline__ void decode_block(int bi, int& b, int& n0) {
    b  = (bi & 7) >> 1;
    n0 = ((((bi & 1) << 7) | (bi >> 3))) * TILE;
}

// ---------------- init kernels ----------------
struct Seg { const float* src; unsigned int dst_off; unsigned int len4; };
struct InitArgs { Seg seg[4]; };

__global__ void init_copy(InitArgs a, unsigned int total4) {
    unsigned int i = blockIdx.x * 256 + threadIdx.x;
    if (i >= total4) return;
#pragma unroll
    for (int s = 0; s < 4; ++s) {
        unsigned int L = a.seg[s].len4;
        if (i < L) {
            const float4 v = ((const float4*)a.seg[s].src)[i];
            *(float4*)&g_ws[a.seg[s].dst_off + 4u * i] = v;
            return;
        }
        i -= L;
    }
}

struct WL { const float* W; int Nsrc; int KB; unsigned int dst; int sz; };
struct WArgs { WL l[6]; };

__global__ void init_wswz(WArgs a, int total) {
    int i = blockIdx.x * 256 + threadIdx.x;
    if (i >= total) return;
#pragma unroll
    for (int s = 0; s < 6; ++s) {
        const int sz = a.l[s].sz;
        if (i < sz) {
            const int KB  = a.l[s].KB;
            const int ct  = i / (KB * 512);
            const int r   = i - ct * KB * 512;
            const int kb  = r >> 9;
            const int r2  = r & 511;
            const int ln  = r2 >> 3;
            const int j   = r2 & 7;
            const int k   = kb * 32 + (ln >> 4) * 8 + j;
            const int n   = ct * 16 + (ln & 15);
            const float v = (n < a.l[s].Nsrc) ? a.l[s].W[k * a.l[s].Nsrc + n] : 0.f;
            g_wf16[a.l[s].dst + i] = (f16)v;
            return;
        }
        i -= sz;
    }
}

// ---------------- MFMA layer1 (N=256, silu) : Xs -> Hs ----------------
template<int KB>
__device__ __forceinline__ void mfma_layer1(const f16 (&Xs)[TILE][XSTR], f16 (&Hs)[TILE][XSTR],
                                            const f16* __restrict__ wp,
                                            const float* __restrict__ bias, int tid) {
    const int wv = tid >> 6, lane = tid & 63, lrow = lane & 15, quad = lane >> 4;
    f32x4 acc[2][4];
#pragma unroll
    for (int m = 0; m < 2; ++m)
#pragma unroll
        for (int c = 0; c < 4; ++c) acc[m][c] = (f32x4){0.f, 0.f, 0.f, 0.f};
#pragma unroll
    for (int kb = 0; kb < KB; ++kb) {
        const f16x8 a0 = *(const f16x8*)&Xs[lrow][kb * 32 + quad * 8];
        const f16x8 a1 = *(const f16x8*)&Xs[16 + lrow][kb * 32 + quad * 8];
#pragma unroll
        for (int c = 0; c < 4; ++c) {
            const f16x8 bf = *(const f16x8*)&wp[(((4 * wv + c) * KB + kb) * 64 + lane) * 8];
            acc[0][c] = __builtin_amdgcn_mfma_f32_16x16x32_f16(a0, bf, acc[0][c], 0, 0, 0);
            acc[1][c] = __builtin_amdgcn_mfma_f32_16x16x32_f16(a1, bf, acc[1][c], 0, 0, 0);
        }
    }
#pragma unroll
    for (int mt = 0; mt < 2; ++mt)
#pragma unroll
        for (int c = 0; c < 4; ++c) {
            const int col = (4 * wv + c) * 16 + lrow;
            const float bb = bias[col];
#pragma unroll
            for (int reg = 0; reg < 4; ++reg)
                Hs[mt * 16 + quad * 4 + reg][col] = (f16)fast_silu(acc[mt][c][reg] + bb);
        }
}

// ---------------- phase A: gather + mod MLP ----------------
__global__ __launch_bounds__(256, 4) void phaseA_kernel(
    const float* __restrict__ hebb, const int* __restrict__ conn,
    const float* __restrict__ db1f, const float* __restrict__ db2f,
    const float* __restrict__ ccf, int t)
{
    const float* h      = g_ws + OFF_H;
    const float* msgs   = g_ws + OFF_MSGS;
    float*       wconn  = g_ws + OFF_WCONN;
    f16*         recv16 = (f16*)(g_ws + OFF_RECV);
    float*       decayb = g_ws + OFF_DECAY;
    const float* identR = g_ws + ((t & 1) ? OFF_ID1 : OFF_ID0);
    float*       accb   = g_ws + OFF_ACC;

    __shared__ f16 Xs[TILE][XSTR];   // 16.9 KB
    __shared__ f16 Hs[TILE][XSTR];   // 16.9 KB (first 8 KB aliased as wsig/idx pre-layer1)
    float* wsigp = (float*)&Hs[0][0];                 // [TILE*KK] f32 (4 KB)
    int*   idxsp = (int*)((char*)&Hs[0][0] + 4096);   // [TILE*KK] int (4 KB)

    const int tid = threadIdx.x;
    int b, n0; decode_block(blockIdx.x, b, n0);

    // ---- staging (all float4) ----
    {   // wconn + conn + hebbian: 1024 elems, 1 float4/thread
        const int i4 = tid * 4;
        const int r = i4 >> 5, k = i4 & 31;
        const size_t rowK = (size_t)(b * NN + n0) * KK + i4;
        const float4 w4 = *(const float4*)&wconn[rowK];
        const int4   c4 = *(const int4*)&conn[(size_t)n0 * KK + i4];
        const float4 hb = *(const float4*)&hebb[rowK];
        float4 s4; s4.x = fast_sigmoid(w4.x); s4.y = fast_sigmoid(w4.y);
                   s4.z = fast_sigmoid(w4.z); s4.w = fast_sigmoid(w4.w);
        *(float4*)&wsigp[i4] = s4;
        *(int4*)&idxsp[i4]   = c4;
        *(f16x4*)&Xs[r][k]   = cvt4(hb);
    }
    {   // h + inject: 2048 elems, 2 float4/thread
        for (int ii = tid; ii < (TILE * DD) / 4; ii += 256) {
            const int i4 = ii * 4;
            const int r = i4 >> 6, d = i4 & 63;
            const float4 hv = *(const float4*)&h[(size_t)(b * NN + n0 + r) * DD + d];
            const float4 cv = *(const float4*)&ccf[(size_t)(b * TT + t) * DSCAN + (n0 >> 9) * DD + d];
            *(f16x4*)&Xs[r][32 + d]  = cvt4(hv);
            *(f16x4*)&Xs[r][192 + d] = cvt4(cv);
        }
    }
    {   // ident: 1024 elems, 1 float4/thread
        const int i4 = tid * 4;
        const int r = i4 >> 5, j = i4 & 31;
        const float4 iv = *(const float4*)&identR[(size_t)n0 * DID + i4];
        *(f16x4*)&Xs[r][96 + j] = cvt4(iv);
    }
    __syncthreads();

    // ---- gather: recv[r][:] = sum_k wsig[r][k] * msgs[b][idx[r][k]][:]  (float4 + shfl reduce)
    {
        const int lane = tid & 63, wv = tid >> 6;
        const int g = lane >> 4, c = lane & 15;      // lane (g,c): neighbors k=g+4j, floats c*4..c*4+3
        const float* mb = msgs + (size_t)b * NN * DD;
        for (int rr = 0; rr < 8; ++rr) {
            const int r = wv * 8 + rr;
            float4 a = {0.f, 0.f, 0.f, 0.f};
#pragma unroll
            for (int j = 0; j < 8; ++j) {
                const int k  = g + 4 * j;
                const int ix = idxsp[r * KK + k];
                const float ws = wsigp[r * KK + k];
                const float4 m = *(const float4*)&mb[(size_t)ix * DD + c * 4];
                a.x = fmaf(ws, m.x, a.x); a.y = fmaf(ws, m.y, a.y);
                a.z = fmaf(ws, m.z, a.z); a.w = fmaf(ws, m.w, a.w);
            }
            a.x += __shfl_xor(a.x, 16); a.y += __shfl_xor(a.y, 16);
            a.z += __shfl_xor(a.z, 16); a.w += __shfl_xor(a.w, 16);
            a.x += __shfl_xor(a.x, 32); a.y += __shfl_xor(a.y, 32);
            a.z += __shfl_xor(a.z, 32); a.w += __shfl_xor(a.w, 32);
            const f16x4 o4 = cvt4(a);
            if (g == 0)      *(f16x4*)&Xs[r][128 + c * 4] = o4;
            else if (g == 1) *(f16x4*)&recv16[(size_t)(b * NN + n0 + r) * DD + c * 4] = o4;
        }
    }
    __syncthreads();   // wsig/idx dead; layer1 may write Hs

    mfma_layer1<8>(Xs, Hs, g_wf16 + OFF16_DW1, db1f, tid);
    __syncthreads();

    // layer2: N=80 (65 used); wave w -> col-tiles (w); waves 0,1 also cover tile 4
    {
        const int wv = tid >> 6, lane = tid & 63, lrow = lane & 15, quad = lane >> 4;
        const f16* wp2 = g_wf16 + OFF16_DW2;
        f32x4 t0 = {0.f,0.f,0.f,0.f}, t1 = t0, t2 = t0;
#pragma unroll
        for (int kb = 0; kb < 8; ++kb) {
            const f16x8 a0 = *(const f16x8*)&Hs[lrow][kb * 32 + quad * 8];
            const f16x8 a1 = *(const f16x8*)&Hs[16 + lrow][kb * 32 + quad * 8];
            const f16x8 b0 = *(const f16x8*)&wp2[((wv * 8 + kb) * 64 + lane) * 8];
            t0 = __builtin_amdgcn_mfma_f32_16x16x32_f16(a0, b0, t0, 0, 0, 0);
            t1 = __builtin_amdgcn_mfma_f32_16x16x32_f16(a1, b0, t1, 0, 0, 0);
            if (wv < 2) {
                const f16x8 b4 = *(const f16x8*)&wp2[((4 * 8 + kb) * 64 + lane) * 8];
                const f16x8 am = (wv == 0) ? a0 : a1;
                t2 = __builtin_amdgcn_mfma_f32_16x16x32_f16(am, b4, t2, 0, 0, 0);
            }
        }
        const int ob = wv * 16 + lrow;
        const float bb = (ob < 65) ? db2f[ob] : 0.f;
#pragma unroll
        for (int mt = 0; mt < 2; ++mt) {
            const f32x4 tv = mt ? t1 : t0;
#pragma unroll
            for (int reg = 0; reg < 4; ++reg) {
                const int n = n0 + mt * 16 + quad * 4 + reg;
                const float v = tv[reg] + bb;
                if (ob < 32)       wconn[((size_t)b * NN + n) * KK + ob] = v;
                else if (ob == 32) decayb[b * NN + n] = fast_sigmoid(v);
                else               accb[((size_t)b * NN + n) * DID + (ob - 33)] = v;
            }
        }
        if (wv < 2) {   // tile 4: only col 64 (ident delta j=31) real
            if (lrow == 0) {
                const float bb4 = db2f[64];
#pragma unroll
                for (int reg = 0; reg < 4; ++reg) {
                    const int n = n0 + wv * 16 + quad * 4 + reg;
                    accb[((size_t)b * NN + n) * DID + 31] = t2[reg] + bb4;
                }
            }
        }
    }
}

// ---------------- phase B: ident merge + state MLP + msg MLP ----------------
__global__ __launch_bounds__(256, 4) void phaseB_kernel(
    const float* __restrict__ sb1f, const float* __restrict__ sb2f,
    const float* __restrict__ mb1f, const float* __restrict__ mb2f,
    const float* __restrict__ ccf, float* __restrict__ out, int t)
{
    float*       h      = g_ws + OFF_H;
    float*       msgs   = g_ws + OFF_MSGS;
    const f16*   recv16 = (const f16*)(g_ws + OFF_RECV);
    const float* decayb = g_ws + OFF_DECAY;
    const float* identR = g_ws + ((t & 1) ? OFF_ID1 : OFF_ID0);
    float*       identW = g_ws + ((t & 1) ? OFF_ID0 : OFF_ID1);
    const float* accb   = g_ws + OFF_ACC;

    __shared__ f16 Xs[TILE][XSTR];
    __shared__ f16 Hs[TILE][XSTR];

    const int tid = threadIdx.x;
    int b, n0; decode_block(blockIdx.x, b, n0);

    // ident_new = ident + mean_b(acc): 1 float4/thread; b==0 blocks publish
    {
        const int i4 = tid * 4;
        const int r = i4 >> 5, j = i4 & 31;
        const size_t base = (size_t)n0 * DID + i4;
        float4 s0 = *(const float4*)&accb[0 * (size_t)NN * DID + base];
        const float4 s1 = *(const float4*)&accb[1 * (size_t)NN * DID + base];
        const float4 s2 = *(const float4*)&accb[2 * (size_t)NN * DID + base];
        const float4 s3 = *(const float4*)&accb[3 * (size_t)NN * DID + base];
        const float4 iv = *(const float4*)&identR[base];
        float4 v;
        v.x = iv.x + 0.25f * (s0.x + s1.x + s2.x + s3.x);
        v.y = iv.y + 0.25f * (s0.y + s1.y + s2.y + s3.y);
        v.z = iv.z + 0.25f * (s0.z + s1.z + s2.z + s3.z);
        v.w = iv.w + 0.25f * (s0.w + s1.w + s2.w + s3.w);
        *(f16x4*)&Xs[r][192 + j] = cvt4(v);
        if (b == 0) *(float4*)&identW[base] = v;
    }
    // recv + inject + h_old: 2 rounds of (f16x4 copy + 2 cvt4)
    for (int ii = tid; ii < (TILE * DD) / 4; ii += 256) {
        const int i4 = ii * 4;
        const int r = i4 >> 6, d = i4 & 63;
        const size_t row = (size_t)(b * NN + n0 + r);
        *(f16x4*)&Xs[r][d] = *(const f16x4*)&recv16[row * DD + d];
        const float4 cv = *(const float4*)&ccf[(size_t)(b * TT + t) * DSCAN + (n0 >> 9) * DD + d];
        const float4 hv = *(const float4*)&h[row * DD + d];
        *(f16x4*)&Xs[r][64 + d]  = cvt4(cv);
        *(f16x4*)&Xs[r][128 + d] = cvt4(hv);
    }
    __syncthreads();

    mfma_layer1<7>(Xs, Hs, g_wf16 + OFF16_SW1, sb1f, tid);
    __syncthreads();

    // state layer2 (N=64): blend + write h/out + stage msg input
    {
        const int wv = tid >> 6, lane = tid & 63, lrow = lane & 15, quad = lane >> 4;
        const f16* wp2 = g_wf16 + OFF16_SW2;
        f32x4 t0 = {0.f,0.f,0.f,0.f}, t1 = t0;
#pragma unroll
        for (int kb = 0; kb < 8; ++kb) {
            const f16x8 a0 = *(const f16x8*)&Hs[lrow][kb * 32 + quad * 8];
            const f16x8 a1 = *(const f16x8*)&Hs[16 + lrow][kb * 32 + quad * 8];
            const f16x8 b0 = *(const f16x8*)&wp2[((wv * 8 + kb) * 64 + lane) * 8];
            t0 = __builtin_amdgcn_mfma_f32_16x16x32_f16(a0, b0, t0, 0, 0, 0);
            t1 = __builtin_amdgcn_mfma_f32_16x16x32_f16(a1, b0, t1, 0, 0, 0);
        }
        const int o = wv * 16 + lrow;
        const float bb = sb2f[o];
#pragma unroll
        for (int mt = 0; mt < 2; ++mt) {
            const f32x4 tv = mt ? t1 : t0;
#pragma unroll
            for (int reg = 0; reg < 4; ++reg) {
                const int r = mt * 16 + quad * 4 + reg;
                const int n = n0 + r;
                const float hw = fast_tanh(tv[reg] + bb);
                const float dc = decayb[b * NN + n];
                const float ho = h[((size_t)b * NN + n) * DD + o];
                const float hn = fmaf(dc, ho, (1.f - dc) * hw);
                h[((size_t)b * NN + n) * DD + o] = hn;
                out[(((size_t)b * TT + t) * NN + n) * DD + o] = hn;
                Xs[r][o] = (f16)hn;          // msg input cols 0..63
            }
        }
        // ident_new -> msg input cols 64..95 (inject cols dead): 1 f16x4/thread
        {
            const int i4 = tid * 4;
            const int r = i4 >> 5, j = i4 & 31;
            *(f16x4*)&Xs[r][64 + j] = *(const f16x4*)&Xs[r][192 + j];
        }
    }
    __syncthreads();

    mfma_layer1<3>(Xs, Hs, g_wf16 + OFF16_MW1, mb1f, tid);
    __syncthreads();

    // msg layer2 (N=64)
    {
        const int wv = tid >> 6, lane = tid & 63, lrow = lane & 15, quad = lane >> 4;
        const f16* wp2 = g_wf16 + OFF16_MW2;
        f32x4 t0 = {0.f,0.f,0.f,0.f}, t1 = t0;
#pragma unroll
        for (int kb = 0; kb < 8; ++kb) {
            const f16x8 a0 = *(const f16x8*)&Hs[lrow][kb * 32 + quad * 8];
            const f16x8 a1 = *(const f16x8*)&Hs[16 + lrow][kb * 32 + quad * 8];
            const f16x8 b0 = *(const f16x8*)&wp2[((wv * 8 + kb) * 64 + lane) * 8];
            t0 = __builtin_amdgcn_mfma_f32_16x16x32_f16(a0, b0, t0, 0, 0, 0);
            t1 = __builtin_amdgcn_mfma_f32_16x16x32_f16(a1, b0, t1, 0, 0, 0);
        }
        const int o = wv * 16 + lrow;
        const float bb = mb2f[o];
#pragma unroll
        for (int mt = 0; mt < 2; ++mt) {
            const f32x4 tv = mt ? t1 : t0;
#pragma unroll
            for (int reg = 0; reg < 4; ++reg) {
                const int n = n0 + mt * 16 + quad * 4 + reg;
                msgs[((size_t)b * NN + n) * DD + o] = fast_tanh(tv[reg] + bb);
            }
        }
    }
}

// ---------------- launch ----------------
extern "C" void kernel_launch(void* const* d_in, const int* in_sizes, int n_in,
                              void* d_out, int out_size, void* d_ws, size_t ws_size,
                              hipStream_t stream)
{
    (void)in_sizes; (void)n_in; (void)out_size; (void)d_ws; (void)ws_size;

    const float* cc   = (const float*)d_in[0];
    const float* h0   = (const float*)d_in[1];
    const float* m0   = (const float*)d_in[2];
    const float* w0   = (const float*)d_in[3];
    const float* hebb = (const float*)d_in[4];
    const float* idn  = (const float*)d_in[5];
    const float* sw1  = (const float*)d_in[6];
    const float* sb1  = (const float*)d_in[7];
    const float* sw2  = (const float*)d_in[8];
    const float* sb2  = (const float*)d_in[9];
    const float* mw1  = (const float*)d_in[10];
    const float* mb1  = (const float*)d_in[11];
    const float* mw2  = (const float*)d_in[12];
    const float* mb2  = (const float*)d_in[13];
    const float* dw1  = (const float*)d_in[14];
    const float* db1  = (const float*)d_in[15];
    const float* dw2  = (const float*)d_in[16];
    const float* db2  = (const float*)d_in[17];
    const int*   conn = (const int*)d_in[18];

    InitArgs ia;
    ia.seg[0] = { h0,  OFF_H,     (BS * NN * DD) / 4 };
    ia.seg[1] = { m0,  OFF_MSGS,  (BS * NN * DD) / 4 };
    ia.seg[2] = { w0,  OFF_WCONN, (BS * NN * KK) / 4 };
    ia.seg[3] = { idn, OFF_ID0,   (NN * DID) / 4 };
    const unsigned int TOT4 = (BS * NN * DD) / 4 * 2 + (BS * NN * KK) / 4 + (NN * DID) / 4;
    init_copy<<<(TOT4 + 255) / 256, 256, 0, stream>>>(ia, TOT4);

    WArgs wa;
    wa.l[0] = { dw1, 256, 8, OFF16_DW1, 16 * 8 * 512 };
    wa.l[1] = { dw2,  65, 8, OFF16_DW2,  5 * 8 * 512 };
    wa.l[2] = { sw1, 256, 7, OFF16_SW1, 16 * 7 * 512 };
    wa.l[3] = { sw2,  64, 8, OFF16_SW2,  4 * 8 * 512 };
    wa.l[4] = { mw1, 256, 3, OFF16_MW1, 16 * 3 * 512 };
    wa.l[5] = { mw2,  64, 8, OFF16_MW2,  4 * 8 * 512 };
    init_wswz<<<(W16_TOTAL + 255) / 256, 256, 0, stream>>>(wa, (int)W16_TOTAL);

    float* outp = (float*)d_out;
    const int grid = BS * (NN / TILE);   // 1024 blocks

    for (int t = 0; t < TT; ++t) {
        phaseA_kernel<<<grid, 256, 0, stream>>>(hebb, conn, db1, db2, cc, t);
        phaseB_kernel<<<grid, 256, 0, stream>>>(sb1, sb2, mb1, mb2, cc, outp, t);
    }
}

// Round 6
// 468.930 us; speedup vs baseline: 4.8241x; 1.1819x over previous
//
#include <hip/hip_runtime.h>

// ---------------- problem constants ----------------
#define NN    8192
#define KK    32
#define DD    64
#define DID   32
#define HD    256
#define BS    4
#define TT    8
#define DSCAN 1024
#define TN    8      // nodes per block
#define ROWS  32     // TN*BS MFMA rows; row r = i*4 + b
#define XSTR  264    // LDS row stride in f16

typedef _Float16 f16;
typedef f16   f16x4 __attribute__((ext_vector_type(4)));
typedef f16   f16x8 __attribute__((ext_vector_type(8)));
typedef float f32x4 __attribute__((ext_vector_type(4)));

// ---------------- device-global workspace ----------------
#define OFF_H      0u          // BS*NN*DD f32 = 2097152
#define OFF_WCONN  2097152u    // BS*NN*KK f32 = 1048576
#define OFF_IDENT  3145728u    // NN*DID f32 = 262144 (updated in place)
#define OFF_MSGS   3407872u    // NN*BS*DD f16 -> 1048576 float slots
#define WS_TOTAL   4456448u

__device__ float g_ws[WS_TOTAL];

// ---------------- pre-swizzled f16 weights (MFMA B-frag order, K-blocks permuted) ----
#define OFF16_DW1  0u        // 16*8*512
#define OFF16_DW2  65536u    // 5*8*512 (65 cols padded to 80)
#define OFF16_SW1  86016u    // 16*7*512
#define OFF16_SW2  143360u   // 4*8*512
#define OFF16_MW1  159744u   // 16*3*512
#define OFF16_MW2  184320u   // 4*8*512
#define W16_TOTAL  200704u

__device__ f16 g_wf16[W16_TOTAL];

// ---------------- numeric helpers ----------------
__device__ __forceinline__ float fast_sigmoid(float x) { return 1.f / (1.f + __expf(-x)); }
__device__ __forceinline__ float fast_silu(float x)    { return x / (1.f + __expf(-x)); }
__device__ __forceinline__ float fast_tanh(float x) {
    float ax = fabsf(x);
    float t  = __expf(-2.f * ax);
    float r  = (1.f - t) / (1.f + t);
    return copysignf(r, x);
}
__device__ __forceinline__ f16x4 cvt4(float4 v) {
    f16x4 o; o[0] = (f16)v.x; o[1] = (f16)v.y; o[2] = (f16)v.z; o[3] = (f16)v.w; return o;
}

// ---------------- init kernels ----------------
struct Seg { const float* src; unsigned int dst_off; unsigned int len4; };
struct InitArgs { Seg seg[3]; };

__global__ void init_copy(InitArgs a, unsigned int total4) {
    unsigned int i = blockIdx.x * 256 + threadIdx.x;
    if (i >= total4) return;
#pragma unroll
    for (int s = 0; s < 3; ++s) {
        unsigned int L = a.seg[s].len4;
        if (i < L) {
            const float4 v = ((const float4*)a.seg[s].src)[i];
            *(float4*)&g_ws[a.seg[s].dst_off + 4u * i] = v;
            return;
        }
        i -= L;
    }
}

// msgs: [b][n][d] f32 -> [n][b][d] f16
__global__ void init_msgs(const float* __restrict__ m0) {
    const unsigned int i = blockIdx.x * 256 + threadIdx.x;   // f16x4 group id
    if (i >= (unsigned)(NN * BS * DD) / 4) return;
    const int n  = i >> 6;
    const int b  = (i >> 4) & 3;
    const int d4 = (i & 15) * 4;
    const float4 v = *(const float4*)&m0[((size_t)b * NN + n) * DD + d4];
    f16* msgs = (f16*)(g_ws + OFF_MSGS);
    *(f16x4*)&msgs[4u * i] = cvt4(v);
}

struct WL { const float* W; int Nsrc; int KB; unsigned int dst; int sz; int perm[8]; };
struct WArgs { WL l[6]; };

__global__ void init_wswz(WArgs a, int total) {
    int i = blockIdx.x * 256 + threadIdx.x;
    if (i >= total) return;
#pragma unroll
    for (int s = 0; s < 6; ++s) {
        const int sz = a.l[s].sz;
        if (i < sz) {
            const int KB  = a.l[s].KB;
            const int ct  = i / (KB * 512);
            const int r   = i - ct * KB * 512;
            const int kb  = r >> 9;
            const int r2  = r & 511;
            const int ln  = r2 >> 3;
            const int j   = r2 & 7;
            const int k   = a.l[s].perm[kb] * 32 + (ln >> 4) * 8 + j;
            const int n   = ct * 16 + (ln & 15);
            const float v = (n < a.l[s].Nsrc) ? a.l[s].W[k * a.l[s].Nsrc + n] : 0.f;
            g_wf16[a.l[s].dst + i] = (f16)v;
            return;
        }
        i -= sz;
    }
}

// ---------------- MFMA layer1 (N=256, silu): Xs cols [KO*32, (KO+KB)*32) -> Hs ----
template<int KB, int KO>
__device__ __forceinline__ void mfma_layer1(const f16 (&Xs)[ROWS][XSTR], f16 (&Hs)[ROWS][XSTR],
                                            const f16* __restrict__ wp,
                                            const float* __restrict__ bias, int tid) {
    const int wv = tid >> 6, lane = tid & 63, lrow = lane & 15, quad = lane >> 4;
    f32x4 acc[2][4];
#pragma unroll
    for (int m = 0; m < 2; ++m)
#pragma unroll
        for (int c = 0; c < 4; ++c) acc[m][c] = (f32x4){0.f, 0.f, 0.f, 0.f};
#pragma unroll
    for (int kb = 0; kb < KB; ++kb) {
        const f16x8 a0 = *(const f16x8*)&Xs[lrow][(KO + kb) * 32 + quad * 8];
        const f16x8 a1 = *(const f16x8*)&Xs[16 + lrow][(KO + kb) * 32 + quad * 8];
#pragma unroll
        for (int c = 0; c < 4; ++c) {
            const f16x8 bf = *(const f16x8*)&wp[(((4 * wv + c) * KB + kb) * 64 + lane) * 8];
            acc[0][c] = __builtin_amdgcn_mfma_f32_16x16x32_f16(a0, bf, acc[0][c], 0, 0, 0);
            acc[1][c] = __builtin_amdgcn_mfma_f32_16x16x32_f16(a1, bf, acc[1][c], 0, 0, 0);
        }
    }
#pragma unroll
    for (int mt = 0; mt < 2; ++mt)
#pragma unroll
        for (int c = 0; c < 4; ++c) {
            const int col = (4 * wv + c) * 16 + lrow;
            const float bb = bias[col];
#pragma unroll
            for (int reg = 0; reg < 4; ++reg)
                Hs[mt * 16 + quad * 4 + reg][col] = (f16)fast_silu(acc[mt][c][reg] + bb);
        }
}

// layer2 pair (N=64 tile per wave, K=256 from Hs)
__device__ __forceinline__ void layer2_pair(const f16 (&Hs)[ROWS][XSTR],
                                            const f16* __restrict__ wp2,
                                            int lane, int lrow, int quad, int wv,
                                            f32x4& t0, f32x4& t1) {
#pragma unroll
    for (int kb = 0; kb < 8; ++kb) {
        const f16x8 a0 = *(const f16x8*)&Hs[lrow][kb * 32 + quad * 8];
        const f16x8 a1 = *(const f16x8*)&Hs[16 + lrow][kb * 32 + quad * 8];
        const f16x8 b0 = *(const f16x8*)&wp2[((wv * 8 + kb) * 64 + lane) * 8];
        t0 = __builtin_amdgcn_mfma_f32_16x16x32_f16(a0, b0, t0, 0, 0, 0);
        t1 = __builtin_amdgcn_mfma_f32_16x16x32_f16(a1, b0, t1, 0, 0, 0);
    }
}

// ---------------- fused step kernel ----------------
// Xs cols: 0..31 hebb | 32..95 h | 96..127 ident/ide2 | 128..191 recv/h_new | 192..255 inject
__global__ __launch_bounds__(256, 4) void step_kernel(
    const float* __restrict__ hebb, const int* __restrict__ conn,
    const float* __restrict__ db1f, const float* __restrict__ db2f,
    const float* __restrict__ sb1f, const float* __restrict__ sb2f,
    const float* __restrict__ mb1f, const float* __restrict__ mb2f,
    const float* __restrict__ ccf, float* __restrict__ out, int step)
{
    float* h      = g_ws + OFF_H;
    float* wconn  = g_ws + OFF_WCONN;
    float* identG = g_ws + OFF_IDENT;
    f16*   msgs   = (f16*)(g_ws + OFF_MSGS);

    __shared__ f16   Xs[ROWS][XSTR];      // 16896 B
    __shared__ f16   Hs[ROWS][XSTR];      // 16896 B
    __shared__ float wsigS[ROWS][36];     // 4608 B (stride 36: 16B-aligned rows, no conflicts)
    __shared__ int   idxS[TN][KK];        // 1024 B
    __shared__ float decayS[ROWS];        // 128 B

    const int tid   = threadIdx.x;
    const int n0    = blockIdx.x * TN;
    const int slice = n0 >> 9;

    // ---- staging ----
    {   // wconn (sigmoid) + hebbian: thread -> (row, k-group)
        const int r = tid >> 3, kg = (tid & 7) * 4;
        const int i = r >> 2, b = r & 3;
        const size_t g = (size_t)(b * NN + n0 + i) * KK + kg;
        const float4 w4 = *(const float4*)&wconn[g];
        const float4 hb = *(const float4*)&hebb[g];
        float4 s4; s4.x = fast_sigmoid(w4.x); s4.y = fast_sigmoid(w4.y);
                   s4.z = fast_sigmoid(w4.z); s4.w = fast_sigmoid(w4.w);
        *(float4*)&wsigS[r][kg] = s4;
        *(f16x4*)&Xs[r][kg]     = cvt4(hb);
    }
    if (tid < 64) {   // conn indices (batch-independent)
        const int i = tid >> 3, kg = (tid & 7) * 4;
        *(int4*)&idxS[i][kg] = *(const int4*)&conn[(size_t)(n0 + i) * KK + kg];
    }
    if (tid < 64) {   // ident -> broadcast to 4 batch rows
        const int i = tid >> 3, jg = (tid & 7) * 4;
        const float4 iv = *(const float4*)&identG[(size_t)(n0 + i) * DID + jg];
        const f16x4 c = cvt4(iv);
#pragma unroll
        for (int b = 0; b < 4; ++b) *(f16x4*)&Xs[i * 4 + b][96 + jg] = c;
    }
#pragma unroll
    for (int ii = tid; ii < ROWS * 16; ii += 256) {   // h + inject
        const int r = ii >> 4, dg = (ii & 15) * 4;
        const int i = r >> 2, b = r & 3;
        const float4 hv = *(const float4*)&h[(size_t)(b * NN + n0 + i) * DD + dg];
        const float4 cv = *(const float4*)&ccf[(size_t)(b * TT + step) * DSCAN + slice * DD + dg];
        *(f16x4*)&Xs[r][32 + dg]  = cvt4(hv);
        *(f16x4*)&Xs[r][192 + dg] = cvt4(cv);
    }
    __syncthreads();

    // ---- gather: recv[i,b,:] = sum_k wsig[i,b,k] * msgs[idx[i][k]][b][:] ----
    {
        const int lane = tid & 63, wv = tid >> 6;
        const int b = lane >> 4, c4 = (lane & 15) * 4;
#pragma unroll
        for (int ii = 0; ii < 2; ++ii) {
            const int i = wv * 2 + ii;
            f32x4 a = {0.f, 0.f, 0.f, 0.f};
#pragma unroll 8
            for (int k = 0; k < KK; ++k) {
                const int ix  = idxS[i][k];
                const float w = wsigS[i * 4 + b][k];
                const f16x4 m = *(const f16x4*)&msgs[((size_t)ix * BS + b) * DD + c4];
                a[0] = fmaf(w, (float)m[0], a[0]); a[1] = fmaf(w, (float)m[1], a[1]);
                a[2] = fmaf(w, (float)m[2], a[2]); a[3] = fmaf(w, (float)m[3], a[3]);
            }
            f16x4 o4; o4[0] = (f16)a[0]; o4[1] = (f16)a[1]; o4[2] = (f16)a[2]; o4[3] = (f16)a[3];
            *(f16x4*)&Xs[i * 4 + b][128 + c4] = o4;
        }
    }
    __syncthreads();

    mfma_layer1<8, 0>(Xs, Hs, g_wf16 + OFF16_DW1, db1f, tid);
    __syncthreads();

    // ---- mod layer2 (N=80): wconn' | decay | ident delta (+intra-thread batch mean) ----
    {
        const int wv = tid >> 6, lane = tid & 63, lrow = lane & 15, quad = lane >> 4;
        const f16* wp2 = g_wf16 + OFF16_DW2;
        f32x4 t0 = {0.f,0.f,0.f,0.f}, t1 = t0, t2 = t0;
#pragma unroll
        for (int kb = 0; kb < 8; ++kb) {
            const f16x8 a0 = *(const f16x8*)&Hs[lrow][kb * 32 + quad * 8];
            const f16x8 a1 = *(const f16x8*)&Hs[16 + lrow][kb * 32 + quad * 8];
            const f16x8 b0 = *(const f16x8*)&wp2[((wv * 8 + kb) * 64 + lane) * 8];
            t0 = __builtin_amdgcn_mfma_f32_16x16x32_f16(a0, b0, t0, 0, 0, 0);
            t1 = __builtin_amdgcn_mfma_f32_16x16x32_f16(a1, b0, t1, 0, 0, 0);
            if (wv < 2) {
                const f16x8 b4 = *(const f16x8*)&wp2[((32 + kb) * 64 + lane) * 8];
                const f16x8 am = (wv == 0) ? a0 : a1;
                t2 = __builtin_amdgcn_mfma_f32_16x16x32_f16(am, b4, t2, 0, 0, 0);
            }
        }
        const int ob = wv * 16 + lrow;
        if (ob < 32) {
            const float bb = db2f[ob];
#pragma unroll
            for (int mt = 0; mt < 2; ++mt) {
                const f32x4 tv = mt ? t1 : t0;
                const int i = quad + 4 * mt;
#pragma unroll
                for (int b = 0; b < 4; ++b)
                    wconn[((size_t)(b * NN + n0 + i)) * KK + ob] = tv[b] + bb;
            }
        } else if (ob == 32) {
            const float bb = db2f[32];
#pragma unroll
            for (int mt = 0; mt < 2; ++mt) {
                const f32x4 tv = mt ? t1 : t0;
#pragma unroll
                for (int b = 0; b < 4; ++b)
                    decayS[(quad + 4 * mt) * 4 + b] = fast_sigmoid(tv[b] + bb);
            }
        } else {
            const int j = ob - 33;
            const float bb = db2f[ob];
#pragma unroll
            for (int mt = 0; mt < 2; ++mt) {
                const f32x4 tv = mt ? t1 : t0;
                const int i = quad + 4 * mt;
                const float m = 0.25f * (tv[0] + tv[1] + tv[2] + tv[3]) + bb;
                const float v = identG[(size_t)(n0 + i) * DID + j] + m;
                identG[(size_t)(n0 + i) * DID + j] = v;
                const f16 vh = (f16)v;
#pragma unroll
                for (int b = 0; b < 4; ++b) Xs[i * 4 + b][96 + j] = vh;
            }
        }
        if (wv < 2 && lrow == 0) {   // col 64 -> ident delta j=31
            const int i = quad + 4 * wv;
            const float m = 0.25f * (t2[0] + t2[1] + t2[2] + t2[3]) + db2f[64];
            const float v = identG[(size_t)(n0 + i) * DID + 31] + m;
            identG[(size_t)(n0 + i) * DID + 31] = v;
            const f16 vh = (f16)v;
#pragma unroll
            for (int b = 0; b < 4; ++b) Xs[i * 4 + b][96 + 31] = vh;
        }
    }
    __syncthreads();

    // ---- state MLP: X cols 32..255 (weights K-permuted at init) ----
    mfma_layer1<7, 1>(Xs, Hs, g_wf16 + OFF16_SW1, sb1f, tid);
    __syncthreads();
    {
        const int wv = tid >> 6, lane = tid & 63, lrow = lane & 15, quad = lane >> 4;
        f32x4 t0 = {0.f,0.f,0.f,0.f}, t1 = t0;
        layer2_pair(Hs, g_wf16 + OFF16_SW2, lane, lrow, quad, wv, t0, t1);
        const int o = wv * 16 + lrow;
        const float bb = sb2f[o];
#pragma unroll
        for (int mt = 0; mt < 2; ++mt) {
            const f32x4 tv = mt ? t1 : t0;
            const int i = quad + 4 * mt;
#pragma unroll
            for (int b = 0; b < 4; ++b) {
                const int r = i * 4 + b;
                const float hw = fast_tanh(tv[b] + bb);
                const float dc = decayS[r];
                const size_t gi = (size_t)(b * NN + n0 + i) * DD + o;
                const float ho = h[gi];
                const float hn = fmaf(dc, ho, (1.f - dc) * hw);
                h[gi] = hn;
                out[((size_t)(b * TT + step) * NN + n0 + i) * DD + o] = hn;
                Xs[r][128 + o] = (f16)hn;   // msg input cols 128..191
            }
        }
    }
    __syncthreads();

    // ---- msg MLP: X cols 96..191 (ide2 | h_new), weights K-permuted ----
    mfma_layer1<3, 3>(Xs, Hs, g_wf16 + OFF16_MW1, mb1f, tid);
    __syncthreads();
    {
        const int wv = tid >> 6, lane = tid & 63, lrow = lane & 15, quad = lane >> 4;
        f32x4 t0 = {0.f,0.f,0.f,0.f}, t1 = t0;
        layer2_pair(Hs, g_wf16 + OFF16_MW2, lane, lrow, quad, wv, t0, t1);
        const int o = wv * 16 + lrow;
        const float bb = mb2f[o];
#pragma unroll
        for (int mt = 0; mt < 2; ++mt) {
            const f32x4 tv = mt ? t1 : t0;
            const int i = quad + 4 * mt;
#pragma unroll
            for (int b = 0; b < 4; ++b)
                msgs[((size_t)(n0 + i) * BS + b) * DD + o] = (f16)fast_tanh(tv[b] + bb);
        }
    }
}

// ---------------- launch ----------------
extern "C" void kernel_launch(void* const* d_in, const int* in_sizes, int n_in,
                              void* d_out, int out_size, void* d_ws, size_t ws_size,
                              hipStream_t stream)
{
    (void)in_sizes; (void)n_in; (void)out_size; (void)d_ws; (void)ws_size;

    const float* cc   = (const float*)d_in[0];
    const float* h0   = (const float*)d_in[1];
    const float* m0   = (const float*)d_in[2];
    const float* w0   = (const float*)d_in[3];
    const float* hebb = (const float*)d_in[4];
    const float* idn  = (const float*)d_in[5];
    const float* sw1  = (const float*)d_in[6];
    const float* sb1  = (const float*)d_in[7];
    const float* sw2  = (const float*)d_in[8];
    const float* sb2  = (const float*)d_in[9];
    const float* mw1  = (const float*)d_in[10];
    const float* mb1  = (const float*)d_in[11];
    const float* mw2  = (const float*)d_in[12];
    const float* mb2  = (const float*)d_in[13];
    const float* dw1  = (const float*)d_in[14];
    const float* db1  = (const float*)d_in[15];
    const float* dw2  = (const float*)d_in[16];
    const float* db2  = (const float*)d_in[17];
    const int*   conn = (const int*)d_in[18];

    InitArgs ia;
    ia.seg[0] = { h0,  OFF_H,     (BS * NN * DD) / 4 };
    ia.seg[1] = { w0,  OFF_WCONN, (BS * NN * KK) / 4 };
    ia.seg[2] = { idn, OFF_IDENT, (NN * DID) / 4 };
    const unsigned int TOT4 = (BS * NN * DD) / 4 + (BS * NN * KK) / 4 + (NN * DID) / 4;
    init_copy<<<(TOT4 + 255) / 256, 256, 0, stream>>>(ia, TOT4);
    init_msgs<<<(NN * BS * DD / 4 + 255) / 256, 256, 0, stream>>>(m0);

    WArgs wa;
    wa.l[0] = { dw1, 256, 8, OFF16_DW1, 16 * 8 * 512, {0,1,2,3,4,5,6,7} };
    wa.l[1] = { dw2,  65, 8, OFF16_DW2,  5 * 8 * 512, {0,1,2,3,4,5,6,7} };
    wa.l[2] = { sw1, 256, 7, OFF16_SW1, 16 * 7 * 512, {4,5,6,0,1,2,3,0} };
    wa.l[3] = { sw2,  64, 8, OFF16_SW2,  4 * 8 * 512, {0,1,2,3,4,5,6,7} };
    wa.l[4] = { mw1, 256, 3, OFF16_MW1, 16 * 3 * 512, {2,0,1,0,0,0,0,0} };
    wa.l[5] = { mw2,  64, 8, OFF16_MW2,  4 * 8 * 512, {0,1,2,3,4,5,6,7} };
    init_wswz<<<(W16_TOTAL + 255) / 256, 256, 0, stream>>>(wa, (int)W16_TOTAL);

    float* outp = (float*)d_out;
    for (int t = 0; t < TT; ++t)
        step_kernel<<<NN / TN, 256, 0, stream>>>(hebb, conn, db1, db2, sb1, sb2,
                                                 mb1, mb2, cc, outp, t);
}